// Round 5
// baseline (973.582 us; speedup 1.0000x reference)
//
#include <hip/hip_runtime.h>

#define T_DIM 512
#define C_DIM 48
#define BPS   64          // bp row stride (padded to 64 so all lanes store)
#define CH    4           // prefetch chunk; ping-pong => 8-step prefetch distance

#if __has_builtin(__builtin_amdgcn_readlane)
#define READLANE_I(v, l) __builtin_amdgcn_readlane((v), (l))
#else
#define READLANE_I(v, l) __shfl((v), (l), 64)
#endif

// Broadcast lane `lane`'s float to the whole wave (wave-uniform result -> SGPR).
__device__ __forceinline__ float bcast_lane(float v, int lane) {
    return __uint_as_float((unsigned)READLANE_I((int)__float_as_uint(v), lane));
}

// One Viterbi step. Scores wave-uniform in sreg[48] (SGPR-homed).
// Lane j computes argmax_i(sreg[i] + tc[i]) via a pairwise TOURNAMENT
// (24-way ILP in round 1; strict '>' taking the right/higher-index side only
// when strictly greater + left-priority merges == jnp.argmax first-occurrence
// tie-break, exactly). bp -> LDS (write-only here). New score vector
// re-broadcast via readlane; no LDS on the recurrence critical path.
#define VSTEP(T_, PV_) do {                                                  \
    float cv[C_DIM];                                                         \
    _Pragma("unroll")                                                        \
    for (int i_ = 0; i_ < C_DIM; ++i_) cv[i_] = sreg[i_] + tc[i_];           \
    float v24[24]; int i24[24];                                              \
    _Pragma("unroll")                                                        \
    for (int k_ = 0; k_ < 24; ++k_) {                                        \
        const bool g_ = cv[2*k_+1] > cv[2*k_];                               \
        v24[k_] = g_ ? cv[2*k_+1] : cv[2*k_];                                \
        i24[k_] = g_ ? (2*k_+1) : (2*k_);                                    \
    }                                                                        \
    float v12[12]; int i12[12];                                              \
    _Pragma("unroll")                                                        \
    for (int k_ = 0; k_ < 12; ++k_) {                                        \
        const bool g_ = v24[2*k_+1] > v24[2*k_];                             \
        v12[k_] = g_ ? v24[2*k_+1] : v24[2*k_];                              \
        i12[k_] = g_ ? i24[2*k_+1] : i24[2*k_];                              \
    }                                                                        \
    float v6[6]; int i6[6];                                                  \
    _Pragma("unroll")                                                        \
    for (int k_ = 0; k_ < 6; ++k_) {                                         \
        const bool g_ = v12[2*k_+1] > v12[2*k_];                             \
        v6[k_] = g_ ? v12[2*k_+1] : v12[2*k_];                               \
        i6[k_] = g_ ? i12[2*k_+1] : i12[2*k_];                               \
    }                                                                        \
    float v3[3]; int i3[3];                                                  \
    _Pragma("unroll")                                                        \
    for (int k_ = 0; k_ < 3; ++k_) {                                         \
        const bool g_ = v6[2*k_+1] > v6[2*k_];                               \
        v3[k_] = g_ ? v6[2*k_+1] : v6[2*k_];                                 \
        i3[k_] = g_ ? i6[2*k_+1] : i6[2*k_];                                 \
    }                                                                        \
    float wv = v3[0]; int wi = i3[0];                                        \
    if (v3[1] > wv) { wv = v3[1]; wi = i3[1]; }                              \
    if (v3[2] > wv) { wv = v3[2]; wi = i3[2]; }                              \
    const float ns_ = wv + (PV_);                                            \
    bp[(T_) * BPS + tid] = (unsigned char)wi;   /* all 64 lanes; pad ok */   \
    _Pragma("unroll")                                                        \
    for (int i_ = 0; i_ < C_DIM; ++i_) sreg[i_] = bcast_lane(ns_, i_);       \
} while (0)

__global__ __launch_bounds__(64) void crf_viterbi(
    const float* __restrict__ pot,     // [B][T][C]
    const int*   __restrict__ seqlen,  // [B][1]
    const float* __restrict__ trans,   // [C][C]
    float*       __restrict__ out)     // [B][T][C] one-hot f32
{
    const int b   = blockIdx.x;
    const int tid = threadIdx.x;
    const int jj  = (tid < C_DIM) ? tid : (C_DIM - 1);  // clamped for safe loads

    __shared__ unsigned char bp[T_DIM * BPS];            // rows 1..L-1 used
    __shared__ __align__(4) unsigned char tags[T_DIM];

    const float* potb = pot + (size_t)b * (T_DIM * C_DIM);
    const int L   = seqlen[b];          // in [1, 511]
    const int thi = L - 1;

    // transitions column j in registers (clamped col for lanes >= 48)
    float tc[C_DIM];
#pragma unroll
    for (int i = 0; i < C_DIM; ++i) tc[i] = trans[i * C_DIM + jj];

    // init: score vector (wave-uniform) = potentials[:,0]
    float sreg[C_DIM];
    {
        const float s0 = potb[jj];
#pragma unroll
        for (int i = 0; i < C_DIM; ++i) sreg[i] = bcast_lane(s0, i);
    }

    const float* pp = potb + jj;

    // ping-pong double-buffered prefetch: no rotation copy, so the compiler
    // never needs a vmcnt(0) drain; each buffer is consumed 2 chunks (8 steps)
    // after its loads are issued.
    float bufA[CH], bufB[CH];
#pragma unroll
    for (int k = 0; k < CH; ++k) {
        int tt = 1 + k;            if (tt > T_DIM - 1) tt = T_DIM - 1;
        bufA[k] = pp[tt * C_DIM];
    }
#pragma unroll
    for (int k = 0; k < CH; ++k) {
        int tt = 1 + CH + k;       if (tt > T_DIM - 1) tt = T_DIM - 1;
        bufB[k] = pp[tt * C_DIM];
    }
    for (int t0 = 1; t0 < L; t0 += 2 * CH) {
#pragma unroll
        for (int k = 0; k < CH; ++k) {
            const int t = t0 + k;
            if (t >= L) break;                 // wave-uniform
            VSTEP(t, bufA[k]);
        }
#pragma unroll
        for (int k = 0; k < CH; ++k) {         // reload A for chunk c+2
            int tt = t0 + 2 * CH + k;  if (tt > T_DIM - 1) tt = T_DIM - 1;
            bufA[k] = pp[tt * C_DIM];
        }
#pragma unroll
        for (int k = 0; k < CH; ++k) {
            const int t = t0 + CH + k;
            if (t >= L) break;                 // wave-uniform
            VSTEP(t, bufB[k]);
        }
#pragma unroll
        for (int k = 0; k < CH; ++k) {         // reload B for chunk c+3
            int tt = t0 + 3 * CH + k;  if (tt > T_DIM - 1) tt = T_DIM - 1;
            bufB[k] = pp[tt * C_DIM];
        }
    }
    __syncthreads();   // phase boundary (single wave; cheap)

    // last_tag = argmax over final scores (wave-uniform values)
    float bv = sreg[0];
    int   bi = 0;
#pragma unroll
    for (int i = 1; i < C_DIM; ++i) {
        if (sreg[i] > bv) { bv = sreg[i]; bi = i; }
    }
    const int last_tag = __builtin_amdgcn_readfirstlane(bi);

    // prefill tags[t] = last_tag for t in [L, T)
    for (int t = L + tid; t < T_DIM; t += 64) tags[t] = (unsigned char)last_tag;

    // serial backtrace: for t = thi..1: tags[t] = y; y = bp[t][y];  then tags[0] = y
    int y = last_tag;  // wave-uniform
    for (int c0 = (thi >> 6) << 6; c0 >= 0; c0 -= 64) {
        int row[64];   // row[k] holds bp[c0+k][jj] in lane jj
#pragma unroll
        for (int k = 0; k < 64; ++k) row[k] = bp[(c0 + k) * BPS + jj];

        int vacc = 0;
#pragma unroll
        for (int k = 63; k >= 0; --k) {
            const int t = c0 + k;
            vacc = (tid == k) ? y : vacc;                        // tags[t] = y (lane k)
            const int ynew = READLANE_I(row[k], y);
            if ((unsigned)(t - 1) < (unsigned)thi) y = ynew;     // update only for t in [1, thi]
        }
        const int tk = c0 + tid;
        if (tk <= thi) tags[tk] = (unsigned char)(vacc & 0xff);
    }
    __syncthreads();   // phase boundary

    // emit one-hot: 4 rows (t) per iteration, 48 lanes x float4 = 768B coalesced
    if (tid < C_DIM) {
        const int r = tid / 12;          // row-in-group 0..3
        const int q = tid - r * 12;      // float4 slot 0..11
        const int cbase = q * 4;
        float* ob = out + (size_t)b * (T_DIM * C_DIM);
        for (int t0 = 0; t0 < T_DIM; t0 += 4) {
            const unsigned int tg4 = *(const unsigned int*)&tags[t0];
            const int mytag = (int)((tg4 >> (r * 8)) & 0xffu);
            float4 v;
            v.x = (cbase + 0 == mytag) ? 1.0f : 0.0f;
            v.y = (cbase + 1 == mytag) ? 1.0f : 0.0f;
            v.z = (cbase + 2 == mytag) ? 1.0f : 0.0f;
            v.w = (cbase + 3 == mytag) ? 1.0f : 0.0f;
            *(float4*)(ob + (size_t)(t0 + r) * C_DIM + cbase) = v;
        }
    }
}

extern "C" void kernel_launch(void* const* d_in, const int* in_sizes, int n_in,
                              void* d_out, int out_size, void* d_ws, size_t ws_size,
                              hipStream_t stream) {
    const float* pot    = (const float*)d_in[0];
    const int*   sl     = (const int*)d_in[1];
    const float* trans  = (const float*)d_in[2];
    float*       out    = (float*)d_out;
    const int B = in_sizes[1];  // sequence_lengths has B elements
    crf_viterbi<<<B, 64, 0, stream>>>(pot, sl, trans, out);
}

// Round 6
// 407.104 us; speedup vs baseline: 2.3915x; 2.3915x over previous
//
#include <hip/hip_runtime.h>

#define T_DIM 512
#define C_DIM 48
#define BPS   64          // bp row stride (padded to 64 so all lanes store)
#define CH    4           // global-prefetch chunk (distance ~4-8 steps)

#if __has_builtin(__builtin_amdgcn_readlane)
#define READLANE_I(v, l) __builtin_amdgcn_readlane((v), (l))
#else
#define READLANE_I(v, l) __shfl((v), (l), 64)
#endif

// Broadcast lane `lane`'s float to the whole wave (wave-uniform result).
__device__ __forceinline__ float bcast_lane(float v, int lane) {
    return __uint_as_float((unsigned)READLANE_I((int)__float_as_uint(v), lane));
}

__device__ __forceinline__ unsigned umin_(unsigned a, unsigned b) { return a < b ? a : b; }

// d == +0 (max-tier) -> i ; d < 0 -> 0xFFFFFFC0 | i (huge).
// Exact: cv-m == +0.0 iff cv == m (RNE); nonzero diffs of O(1..100)-magnitude
// floats are >= ~1e-6, never denormal, so the sign bit is a reliable flag.
__device__ __forceinline__ unsigned enc_idx(float d, unsigned i) {
    unsigned s = (unsigned)(((int)__float_as_int(d)) >> 31);   // 0 or 0xFFFFFFFF
    return (s & 0xFFFFFFC0u) | i;
}

#define MAX3(a, b, c) fmaxf(fmaxf((a), (b)), (c))
#define EMIN3(I_) umin_(umin_(enc_idx(cv[(I_)] - m_, (I_)),                 \
                              enc_idx(cv[(I_) + 1] - m_, (I_) + 1)),        \
                        enc_idx(cv[(I_) + 2] - m_, (I_) + 2))

// One Viterbi step. Scores wave-uniform in sreg[48]. Lane j computes
// argmax_i(sreg[i] + tc[i]) via hazard-free VALU trees:
//   value  : v_max3_f32 tree (exact max, no scalar-reg writes)
//   argmax : sign-encode (cv_i - m) | i, v_min3_u32 tree
//            -> lowest max-tier index == jnp.argmax first-occurrence, exactly.
// bp -> LDS (write-only, off critical path); new score re-broadcast via
// readlane (the only scalar writes in the loop).
#define VSTEP(T_, PV_) do {                                                  \
    float cv[C_DIM];                                                         \
    _Pragma("unroll")                                                        \
    for (int i_ = 0; i_ < C_DIM; ++i_) cv[i_] = sreg[i_] + tc[i_];           \
    float A0  = MAX3(cv[0],  cv[1],  cv[2]);                                 \
    float A1  = MAX3(cv[3],  cv[4],  cv[5]);                                 \
    float A2  = MAX3(cv[6],  cv[7],  cv[8]);                                 \
    float A3  = MAX3(cv[9],  cv[10], cv[11]);                                \
    float A4  = MAX3(cv[12], cv[13], cv[14]);                                \
    float A5  = MAX3(cv[15], cv[16], cv[17]);                                \
    float A6  = MAX3(cv[18], cv[19], cv[20]);                                \
    float A7  = MAX3(cv[21], cv[22], cv[23]);                                \
    float A8  = MAX3(cv[24], cv[25], cv[26]);                                \
    float A9  = MAX3(cv[27], cv[28], cv[29]);                                \
    float A10 = MAX3(cv[30], cv[31], cv[32]);                                \
    float A11 = MAX3(cv[33], cv[34], cv[35]);                                \
    float A12 = MAX3(cv[36], cv[37], cv[38]);                                \
    float A13 = MAX3(cv[39], cv[40], cv[41]);                                \
    float A14 = MAX3(cv[42], cv[43], cv[44]);                                \
    float A15 = MAX3(cv[45], cv[46], cv[47]);                                \
    float B0 = MAX3(A0,  A1,  A2);                                           \
    float B1 = MAX3(A3,  A4,  A5);                                           \
    float B2 = MAX3(A6,  A7,  A8);                                           \
    float B3 = MAX3(A9,  A10, A11);                                          \
    float B4 = MAX3(A12, A13, A14);                                          \
    float Cx0 = MAX3(B0, B1, B2);                                            \
    float Cx1 = MAX3(B3, B4, A15);                                           \
    const float m_ = fmaxf(Cx0, Cx1);                                        \
    unsigned U0  = EMIN3(0);   unsigned U1  = EMIN3(3);                      \
    unsigned U2  = EMIN3(6);   unsigned U3  = EMIN3(9);                      \
    unsigned U4  = EMIN3(12);  unsigned U5  = EMIN3(15);                     \
    unsigned U6  = EMIN3(18);  unsigned U7  = EMIN3(21);                     \
    unsigned U8  = EMIN3(24);  unsigned U9  = EMIN3(27);                     \
    unsigned U10 = EMIN3(30);  unsigned U11 = EMIN3(33);                     \
    unsigned U12 = EMIN3(36);  unsigned U13 = EMIN3(39);                     \
    unsigned U14 = EMIN3(42);  unsigned U15 = EMIN3(45);                     \
    unsigned V0 = umin_(umin_(U0,  U1),  U2);                                \
    unsigned V1 = umin_(umin_(U3,  U4),  U5);                                \
    unsigned V2 = umin_(umin_(U6,  U7),  U8);                                \
    unsigned V3 = umin_(umin_(U9,  U10), U11);                               \
    unsigned V4 = umin_(umin_(U12, U13), U14);                               \
    unsigned W0 = umin_(umin_(V0, V1), V2);                                  \
    unsigned W1 = umin_(umin_(V3, V4), U15);                                 \
    const unsigned wi_ = umin_(W0, W1);                                      \
    const float ns_ = m_ + (PV_);                                            \
    bp[(T_) * BPS + tid] = (unsigned char)wi_;  /* all 64 lanes; pad ok */   \
    _Pragma("unroll")                                                        \
    for (int i_ = 0; i_ < C_DIM; ++i_) sreg[i_] = bcast_lane(ns_, i_);       \
} while (0)

__global__ __launch_bounds__(64) void crf_viterbi(
    const float* __restrict__ pot,     // [B][T][C]
    const int*   __restrict__ seqlen,  // [B][1]
    const float* __restrict__ trans,   // [C][C]
    float*       __restrict__ out)     // [B][T][C] one-hot f32
{
    const int b   = blockIdx.x;
    const int tid = threadIdx.x;
    const int jj  = (tid < C_DIM) ? tid : (C_DIM - 1);  // clamped for safe loads

    __shared__ unsigned char bp[T_DIM * BPS];            // rows 1..L-1 used
    __shared__ __align__(4) unsigned char tags[T_DIM];

    const float* potb = pot + (size_t)b * (T_DIM * C_DIM);
    const int L   = seqlen[b];          // in [1, 511]
    const int thi = L - 1;

    // transitions column j in registers (clamped col for lanes >= 48)
    float tc[C_DIM];
#pragma unroll
    for (int i = 0; i < C_DIM; ++i) tc[i] = trans[i * C_DIM + jj];

    // init: score vector (wave-uniform) = potentials[:,0]
    float sreg[C_DIM];
    {
        const float s0 = potb[jj];
#pragma unroll
        for (int i = 0; i < C_DIM; ++i) sreg[i] = bcast_lane(s0, i);
    }

    const float* pp = potb + jj;

    // software-pipelined forward loop: prefetch chunk CH ahead (clamped rows)
    float pb[CH];
#pragma unroll
    for (int k = 0; k < CH; ++k) {
        int tt = 1 + k; if (tt > T_DIM - 1) tt = T_DIM - 1;
        pb[k] = pp[tt * C_DIM];
    }
    for (int t0 = 1; t0 < L; t0 += CH) {
        float nb[CH];
#pragma unroll
        for (int k = 0; k < CH; ++k) {
            int tt = t0 + CH + k; if (tt > T_DIM - 1) tt = T_DIM - 1;
            nb[k] = pp[tt * C_DIM];
        }
#pragma unroll
        for (int k = 0; k < CH; ++k) {
            const int t = t0 + k;
            if (t >= L) break;           // wave-uniform branch
            VSTEP(t, pb[k]);
        }
#pragma unroll
        for (int k = 0; k < CH; ++k) pb[k] = nb[k];
    }
    __syncthreads();   // phase boundary (single wave; cheap)

    // last_tag = argmax over final scores (wave-uniform values)
    float bv = sreg[0];
    int   bi = 0;
#pragma unroll
    for (int i = 1; i < C_DIM; ++i) {
        if (sreg[i] > bv) { bv = sreg[i]; bi = i; }
    }
    const int last_tag = __builtin_amdgcn_readfirstlane(bi);

    // prefill tags[t] = last_tag for t in [L, T)
    for (int t = L + tid; t < T_DIM; t += 64) tags[t] = (unsigned char)last_tag;

    // serial backtrace: for t = thi..1: tags[t] = y; y = bp[t][y];  then tags[0] = y
    int y = last_tag;  // wave-uniform
    for (int c0 = (thi >> 6) << 6; c0 >= 0; c0 -= 64) {
        int row[64];   // row[k] holds bp[c0+k][jj] in lane jj
#pragma unroll
        for (int k = 0; k < 64; ++k) row[k] = bp[(c0 + k) * BPS + jj];

        int vacc = 0;
#pragma unroll
        for (int k = 63; k >= 0; --k) {
            const int t = c0 + k;
            vacc = (tid == k) ? y : vacc;                        // tags[t] = y (lane k)
            const int ynew = READLANE_I(row[k], y);
            if ((unsigned)(t - 1) < (unsigned)thi) y = ynew;     // update only for t in [1, thi]
        }
        const int tk = c0 + tid;
        if (tk <= thi) tags[tk] = (unsigned char)(vacc & 0xff);
    }
    __syncthreads();   // phase boundary

    // emit one-hot: 4 rows (t) per iteration, 48 lanes x float4 = 768B coalesced
    if (tid < C_DIM) {
        const int r = tid / 12;          // row-in-group 0..3
        const int q = tid - r * 12;      // float4 slot 0..11
        const int cbase = q * 4;
        float* ob = out + (size_t)b * (T_DIM * C_DIM);
        for (int t0 = 0; t0 < T_DIM; t0 += 4) {
            const unsigned int tg4 = *(const unsigned int*)&tags[t0];
            const int mytag = (int)((tg4 >> (r * 8)) & 0xffu);
            float4 v;
            v.x = (cbase + 0 == mytag) ? 1.0f : 0.0f;
            v.y = (cbase + 1 == mytag) ? 1.0f : 0.0f;
            v.z = (cbase + 2 == mytag) ? 1.0f : 0.0f;
            v.w = (cbase + 3 == mytag) ? 1.0f : 0.0f;
            *(float4*)(ob + (size_t)(t0 + r) * C_DIM + cbase) = v;
        }
    }
}

extern "C" void kernel_launch(void* const* d_in, const int* in_sizes, int n_in,
                              void* d_out, int out_size, void* d_ws, size_t ws_size,
                              hipStream_t stream) {
    const float* pot    = (const float*)d_in[0];
    const int*   sl     = (const int*)d_in[1];
    const float* trans  = (const float*)d_in[2];
    float*       out    = (float*)d_out;
    const int B = in_sizes[1];  // sequence_lengths has B elements
    crf_viterbi<<<B, 64, 0, stream>>>(pot, sl, trans, out);
}